// Round 1
// baseline (1594.293 us; speedup 1.0000x reference)
//
#include <hip/hip_runtime.h>
#include <math.h>

#define T_LEN   2048
#define NKH     16
#define NVH     32
#define HD      64
#define KEY_DIM 1024
#define VAL_DIM 2048
#define CONV_DIM 4096

typedef float fl4 __attribute__((ext_vector_type(4)));

__device__ __forceinline__ float sigmoid_f(float x) { return 1.f / (1.f + __expf(-x)); }

// ---------------------------------------------------------------------------
// Kernel 1: causal conv1d (W=4) + silu + head split + qk l2norm + gates.
// One block per timestep t; 256 threads; thread handles 16 consecutive dims.
// Heads (64 dims) align with 4-lane groups -> shfl_xor(1,2) reductions.
// ---------------------------------------------------------------------------
__global__ __launch_bounds__(256) void prep_kernel(
    const float* __restrict__ x,        // [T, 4096]
    const float* __restrict__ cs,       // [3, 4096] conv_state_in[0]
    const float* __restrict__ w,        // [4096, 4]
    const float* __restrict__ b,        // [T, 32]
    const float* __restrict__ a,        // [T, 32]
    const float* __restrict__ A_log,    // [32]
    const float* __restrict__ dt_bias,  // [32]
    float* __restrict__ qn,             // [T, 16, 64]
    float* __restrict__ kn,             // [T, 16, 64]
    float* __restrict__ vo,             // [T, 32, 64]
    float* __restrict__ g,              // [T, 32]
    float* __restrict__ beta)           // [T, 32]
{
    const int t   = blockIdx.x;
    const int tid = threadIdx.x;
    const int d0  = tid * 16;

    fl4 r4[4];
    #pragma unroll
    for (int grp = 0; grp < 4; ++grp) {
        const int d = d0 + grp * 4;
        fl4 xv[4], wq[4];
        #pragma unroll
        for (int wi = 0; wi < 4; ++wi) {
            const int row = t - 3 + wi;
            const float* src = (row >= 0) ? (x + (size_t)row * CONV_DIM + d)
                                          : (cs + (size_t)(row + 3) * CONV_DIM + d);
            xv[wi] = *(const fl4*)src;
        }
        #pragma unroll
        for (int j = 0; j < 4; ++j) wq[j] = *(const fl4*)(w + (size_t)(d + j) * 4);
        #pragma unroll
        for (int j = 0; j < 4; ++j) {
            float acc = xv[0][j] * wq[j][0];
            acc = fmaf(xv[1][j], wq[j][1], acc);
            acc = fmaf(xv[2][j], wq[j][2], acc);
            acc = fmaf(xv[3][j], wq[j][3], acc);
            // silu
            r4[grp][j] = acc * sigmoid_f(acc);
        }
    }

    if (tid < 128) {
        // q (tid<64) or k (64<=tid<128) region: l2norm over the 64-dim head.
        float ss = 0.f;
        #pragma unroll
        for (int grp = 0; grp < 4; ++grp)
            #pragma unroll
            for (int j = 0; j < 4; ++j) ss = fmaf(r4[grp][j], r4[grp][j], ss);
        ss += __shfl_xor(ss, 1);
        ss += __shfl_xor(ss, 2);
        const bool is_q = (tid < 64);
        float scale = (is_q ? 0.125f : 1.0f) / sqrtf(ss + 1e-6f);
        float* dst = is_q ? (qn + (size_t)t * KEY_DIM + d0)
                          : (kn + (size_t)t * KEY_DIM + (d0 - KEY_DIM));
        #pragma unroll
        for (int grp = 0; grp < 4; ++grp) {
            fl4 o;
            #pragma unroll
            for (int j = 0; j < 4; ++j) o[j] = r4[grp][j] * scale;
            *(fl4*)(dst + grp * 4) = o;
        }
    } else {
        // v region: plain silu output
        float* dst = vo + (size_t)t * VAL_DIM + (d0 - 2 * KEY_DIM);
        #pragma unroll
        for (int grp = 0; grp < 4; ++grp) *(fl4*)(dst + grp * 4) = r4[grp];
    }

    // gates: 32 lanes of wave 0
    if (tid < 32) {
        float av = a[(size_t)t * NVH + tid] + dt_bias[tid];
        // stable softplus = max(x,0) + log1p(exp(-|x|))
        float sp = fmaxf(av, 0.f) + log1pf(__expf(-fabsf(av)));
        g[(size_t)t * NVH + tid]    = -__expf(A_log[tid]) * sp;
        beta[(size_t)t * NVH + tid] = sigmoid_f(b[(size_t)t * NVH + tid]);
    }
}

// ---------------------------------------------------------------------------
// Kernel 2: gated delta-rule scan. One block per v-head (32 blocks), 256 thr
// = 4 waves (1/SIMD). Thread (vcol = tid>>2, kg = tid&3) owns S[kg*16 ..
// kg*16+15][vcol] in registers. Reductions over k are shfl_xor(1,2) within a
// lane quad. k/q/v/g/beta are double-buffer prefetched one step ahead.
// ---------------------------------------------------------------------------
#define LOADSTEP(KA, QA, VV, GG, BB, tt) {                                     \
    _Pragma("unroll")                                                          \
    for (int i = 0; i < 4; ++i) {                                              \
        KA[i] = *(const fl4*)(kp + (size_t)(tt) * KEY_DIM + i * 4);            \
        QA[i] = *(const fl4*)(qp + (size_t)(tt) * KEY_DIM + i * 4);            \
    }                                                                          \
    VV = vp[(size_t)(tt) * VAL_DIM];                                           \
    GG = gp[(size_t)(tt) * NVH];                                               \
    BB = bp[(size_t)(tt) * NVH];                                               \
}

#define COMPUTE(KA, QA, VV, GG, BB, tt) {                                      \
    const float dec = __expf(GG);                                              \
    float c0 = 0.f, c1 = 0.f, c2 = 0.f, c3 = 0.f;                              \
    _Pragma("unroll")                                                          \
    for (int i = 0; i < 4; ++i) {                                              \
        S[i*4+0] *= dec; S[i*4+1] *= dec; S[i*4+2] *= dec; S[i*4+3] *= dec;    \
        c0 = fmaf(S[i*4+0], KA[i][0], c0);                                     \
        c1 = fmaf(S[i*4+1], KA[i][1], c1);                                     \
        c2 = fmaf(S[i*4+2], KA[i][2], c2);                                     \
        c3 = fmaf(S[i*4+3], KA[i][3], c3);                                     \
    }                                                                          \
    float kv = (c0 + c1) + (c2 + c3);                                          \
    kv += __shfl_xor(kv, 1);                                                   \
    kv += __shfl_xor(kv, 2);                                                   \
    const float u = BB * (VV - kv);                                            \
    float o0 = 0.f, o1 = 0.f, o2 = 0.f, o3 = 0.f;                              \
    _Pragma("unroll")                                                          \
    for (int i = 0; i < 4; ++i) {                                              \
        S[i*4+0] = fmaf(KA[i][0], u, S[i*4+0]);                                \
        S[i*4+1] = fmaf(KA[i][1], u, S[i*4+1]);                                \
        S[i*4+2] = fmaf(KA[i][2], u, S[i*4+2]);                                \
        S[i*4+3] = fmaf(KA[i][3], u, S[i*4+3]);                                \
        o0 = fmaf(S[i*4+0], QA[i][0], o0);                                     \
        o1 = fmaf(S[i*4+1], QA[i][1], o1);                                     \
        o2 = fmaf(S[i*4+2], QA[i][2], o2);                                     \
        o3 = fmaf(S[i*4+3], QA[i][3], o3);                                     \
    }                                                                          \
    float oo = (o0 + o1) + (o2 + o3);                                          \
    oo += __shfl_xor(oo, 1);                                                   \
    oo += __shfl_xor(oo, 2);                                                   \
    if (kg == 0) op[(size_t)(tt) * VAL_DIM] = oo;                              \
}

__global__ __launch_bounds__(256) void scan_kernel(
    const float* __restrict__ qn,   // [T, 16, 64]
    const float* __restrict__ kn,   // [T, 16, 64]
    const float* __restrict__ v,    // [T, 32, 64]
    const float* __restrict__ g,    // [T, 32]
    const float* __restrict__ bet,  // [T, 32]
    const float* __restrict__ rs0,  // [32, 64, 64] initial state
    float* __restrict__ out)        // [T, 32, 64]
{
    const int h    = blockIdx.x;   // v-head 0..31
    const int kh   = h >> 1;       // k-head (rep=2)
    const int tid  = threadIdx.x;
    const int vcol = tid >> 2;     // 0..63
    const int kg   = tid & 3;      // 0..3

    float S[16];
    #pragma unroll
    for (int j = 0; j < 16; ++j)
        S[j] = rs0[((size_t)h * HD + (kg * 16 + j)) * HD + vcol];

    const float* kp = kn + (size_t)kh * HD + kg * 16;
    const float* qp = qn + (size_t)kh * HD + kg * 16;
    const float* vp = v + (size_t)h * HD + vcol;
    const float* gp = g + h;
    const float* bp = bet + h;
    float*       op = out + (size_t)h * HD + vcol;

    fl4 ka0[4], qa0[4]; float vv0, gg0, bb0;
    fl4 ka1[4], qa1[4]; float vv1, gg1, bb1;

    LOADSTEP(ka0, qa0, vv0, gg0, bb0, 0);
    for (int t = 0; t < T_LEN; t += 2) {
        LOADSTEP(ka1, qa1, vv1, gg1, bb1, t + 1);
        COMPUTE(ka0, qa0, vv0, gg0, bb0, t);
        const int t2 = (t + 2 < T_LEN) ? (t + 2) : (T_LEN - 1);
        LOADSTEP(ka0, qa0, vv0, gg0, bb0, t2);
        COMPUTE(ka1, qa1, vv1, gg1, bb1, t + 1);
    }
}

// ---------------------------------------------------------------------------
extern "C" void kernel_launch(void* const* d_in, const int* in_sizes, int n_in,
                              void* d_out, int out_size, void* d_ws, size_t ws_size,
                              hipStream_t stream)
{
    const float* x       = (const float*)d_in[0];  // mixed_qkv [T,4096]
    const float* cs      = (const float*)d_in[1];  // conv_state_in [1,3,4096]
    const float* rs0     = (const float*)d_in[2];  // recurrent_state_in [1,32,64,64]
    const float* b       = (const float*)d_in[3];  // [T,32]
    const float* a       = (const float*)d_in[4];  // [T,32]
    const float* w       = (const float*)d_in[5];  // [4096,4]
    const float* A_log   = (const float*)d_in[6];  // [32]
    const float* dt_bias = (const float*)d_in[7];  // [32]
    float* out = (float*)d_out;

    float* ws = (float*)d_ws;
    float* qn = ws;                               // 2048*1024
    float* kn = qn + (size_t)T_LEN * KEY_DIM;     // 2048*1024
    float* vo = kn + (size_t)T_LEN * KEY_DIM;     // 2048*2048
    float* g  = vo + (size_t)T_LEN * VAL_DIM;     // 2048*32
    float* be = g  + (size_t)T_LEN * NVH;         // 2048*32

    prep_kernel<<<T_LEN, 256, 0, stream>>>(x, cs, w, b, a, A_log, dt_bias,
                                           qn, kn, vo, g, be);
    scan_kernel<<<NVH, 256, 0, stream>>>(qn, kn, vo, g, be, rs0, out);
}

// Round 2
// 598.876 us; speedup vs baseline: 2.6621x; 2.6621x over previous
//
#include <hip/hip_runtime.h>
#include <math.h>

#define T_LEN   2048
#define NKH     16
#define NVH     32
#define HD      64
#define KEY_DIM 1024
#define VAL_DIM 2048
#define CONV_DIM 4096
#define NCHUNK  32
#define CL      64

typedef float fl4 __attribute__((ext_vector_type(4)));

__device__ __forceinline__ float sigmoid_f(float x) { return 1.f / (1.f + __expf(-x)); }

// ---------------------------------------------------------------------------
// Kernel 1: causal conv1d (W=4) + silu + head split + qk l2norm + gates.
// ---------------------------------------------------------------------------
__global__ __launch_bounds__(256) void prep_kernel(
    const float* __restrict__ x,        // [T, 4096]
    const float* __restrict__ cs,       // [3, 4096]
    const float* __restrict__ w,        // [4096, 4]
    const float* __restrict__ b,        // [T, 32]
    const float* __restrict__ a,        // [T, 32]
    const float* __restrict__ A_log,    // [32]
    const float* __restrict__ dt_bias,  // [32]
    float* __restrict__ qn,             // [T, 16, 64]
    float* __restrict__ kn,             // [T, 16, 64]
    float* __restrict__ vo,             // [T, 32, 64]
    float* __restrict__ g,              // [T, 32]
    float* __restrict__ beta)           // [T, 32]
{
    const int t   = blockIdx.x;
    const int tid = threadIdx.x;
    const int d0  = tid * 16;

    fl4 r4[4];
    #pragma unroll
    for (int grp = 0; grp < 4; ++grp) {
        const int d = d0 + grp * 4;
        fl4 xv[4], wq[4];
        #pragma unroll
        for (int wi = 0; wi < 4; ++wi) {
            const int row = t - 3 + wi;
            const float* src = (row >= 0) ? (x + (size_t)row * CONV_DIM + d)
                                          : (cs + (size_t)(row + 3) * CONV_DIM + d);
            xv[wi] = *(const fl4*)src;
        }
        #pragma unroll
        for (int j = 0; j < 4; ++j) wq[j] = *(const fl4*)(w + (size_t)(d + j) * 4);
        #pragma unroll
        for (int j = 0; j < 4; ++j) {
            float acc = xv[0][j] * wq[j][0];
            acc = fmaf(xv[1][j], wq[j][1], acc);
            acc = fmaf(xv[2][j], wq[j][2], acc);
            acc = fmaf(xv[3][j], wq[j][3], acc);
            r4[grp][j] = acc * sigmoid_f(acc);
        }
    }

    if (tid < 128) {
        float ss = 0.f;
        #pragma unroll
        for (int grp = 0; grp < 4; ++grp)
            #pragma unroll
            for (int j = 0; j < 4; ++j) ss = fmaf(r4[grp][j], r4[grp][j], ss);
        ss += __shfl_xor(ss, 1);
        ss += __shfl_xor(ss, 2);
        const bool is_q = (tid < 64);
        float scale = (is_q ? 0.125f : 1.0f) / sqrtf(ss + 1e-6f);
        float* dst = is_q ? (qn + (size_t)t * KEY_DIM + d0)
                          : (kn + (size_t)t * KEY_DIM + (d0 - KEY_DIM));
        #pragma unroll
        for (int grp = 0; grp < 4; ++grp) {
            fl4 o;
            #pragma unroll
            for (int j = 0; j < 4; ++j) o[j] = r4[grp][j] * scale;
            *(fl4*)(dst + grp * 4) = o;
        }
    } else {
        float* dst = vo + (size_t)t * VAL_DIM + (d0 - 2 * KEY_DIM);
        #pragma unroll
        for (int grp = 0; grp < 4; ++grp) *(fl4*)(dst + grp * 4) = r4[grp];
    }

    if (tid < 32) {
        float av = a[(size_t)t * NVH + tid] + dt_bias[tid];
        float sp = fmaxf(av, 0.f) + log1pf(__expf(-fabsf(av)));
        g[(size_t)t * NVH + tid]    = -__expf(A_log[tid]) * sp;
        beta[(size_t)t * NVH + tid] = sigmoid_f(b[(size_t)t * NVH + tid]);
    }
}

// ---------------------------------------------------------------------------
// Kernel 2 (phase 1): per (chunk c, v-head h), fully parallel.
// Builds G (cumsum g), gamma, A = beta*exp(dG)*KK^T (strict lower),
// T = (I+A)^{-1} (blocked tri inversion), then:
//   MTt[s][t] = (M*T)[t][s]  with M[t][s] = exp(G_t-G_s)*(q_t.k_s), s<=t
//   SUt[s][d] = sum_t exp(G_end-G_t)*k_t[d]*T[t][s]
//   KT/QT = packed transposes of the chunk's K,Q (per k-head)
// ---------------------------------------------------------------------------
__global__ __launch_bounds__(256) void phase1_kernel(
    const float* __restrict__ qn, const float* __restrict__ kn,
    const float* __restrict__ gws, const float* __restrict__ bws,
    float* __restrict__ gam_g, float* __restrict__ KT_g, float* __restrict__ QT_g,
    float* __restrict__ MTt_g, float* __restrict__ SUt_g)
{
    const int bid = blockIdx.x;
    const int c = bid >> 5, h = bid & 31, kh = h >> 1;
    const int tid = threadIdx.x, lane = tid & 63, wv = tid >> 6;

    __shared__ float Ks[64][68], Qs[64][68], Am[64][68], Tm[64][68], Mm[64][68];
    __shared__ float Gs[64], Dend[64], Bet[64];
    __shared__ float Xs[4][16][17];

    // load K,Q tiles (row-major, stride-68 pad; 68%4==0 keeps fl4 aligned)
    #pragma unroll
    for (int p = 0; p < 4; ++p) {
        int idx = p * 256 + tid;
        int t = idx >> 4, i4 = (idx & 15) * 4;
        *(fl4*)&Ks[t][i4] = *(const fl4*)&kn[(size_t)(c*64+t)*KEY_DIM + kh*64 + i4];
        *(fl4*)&Qs[t][i4] = *(const fl4*)&qn[(size_t)(c*64+t)*KEY_DIM + kh*64 + i4];
    }
    // Tm = I
    for (int idx = tid; idx < 64*64; idx += 256) {
        int t = idx >> 6, s = idx & 63;
        Tm[t][s] = (t == s) ? 1.f : 0.f;
    }
    // gates: wave 0 does the 64-step inclusive cumsum via shfl_up
    if (tid < 64) {
        float gv = gws[(size_t)(c*64+lane)*NVH + h];
        #pragma unroll
        for (int d = 1; d < 64; d <<= 1) {
            float nv = __shfl_up(gv, d);
            if (lane >= d) gv += nv;
        }
        Gs[lane] = gv;
        float g63 = __shfl(gv, 63);
        Dend[lane] = __expf(g63 - gv);
        Bet[lane] = bws[(size_t)(c*64+lane)*NVH + h];
        gam_g[(size_t)(c*NVH+h)*64 + lane] = __expf(gv);
    }
    __syncthreads();

    // A = beta*exp(dG)*K K^T (strict lower), M = exp(dG)*Q K^T (incl lower)
    {
        float accK[16], accQ[16];
        #pragma unroll
        for (int j = 0; j < 16; ++j) { accK[j] = 0.f; accQ[j] = 0.f; }
        const int t = lane, sbase = wv * 16;
        for (int i4 = 0; i4 < 64; i4 += 4) {
            fl4 kt = *(const fl4*)&Ks[t][i4];
            fl4 qt = *(const fl4*)&Qs[t][i4];
            #pragma unroll
            for (int sj = 0; sj < 16; ++sj) {
                fl4 ks = *(const fl4*)&Ks[sbase + sj][i4];   // broadcast
                accK[sj] += kt[0]*ks[0] + kt[1]*ks[1] + kt[2]*ks[2] + kt[3]*ks[3];
                accQ[sj] += qt[0]*ks[0] + qt[1]*ks[1] + qt[2]*ks[2] + qt[3]*ks[3];
            }
        }
        const float gt = Gs[t], bt = Bet[t];
        #pragma unroll
        for (int sj = 0; sj < 16; ++sj) {
            int s = sbase + sj;
            float e = __expf(gt - Gs[s]);
            Am[t][s] = (s < t)  ? bt * e * accK[sj] : 0.f;
            Mm[t][s] = (s <= t) ? e * accQ[sj] : 0.f;
        }
    }
    __syncthreads();

    // T = (I+A)^{-1}: 4 diagonal 16x16 blocks by forward substitution (wave-parallel)
    if (lane < 16) {
        const int base = wv * 16;
        const int sj = lane, s = base + sj;
        for (int tl = 1; tl < 16; ++tl) {
            int t = base + tl;
            if (sj < tl) {
                float acc = 0.f;
                for (int il = sj; il < tl; ++il)
                    acc += Am[t][base + il] * Tm[base + il][s];
                Tm[t][s] = -acc;   // column s is lane-private throughout
            }
        }
    }
    // off-diagonal blocks, level by level: T[I][J] = -T[I][I]*(sum_K A[I][K]*T[K][J])
    for (int L = 1; L <= 3; ++L) {
        __syncthreads();
        if (wv < 4 - L) {
            const int J = wv, I = wv + L;
            const int r = lane & 15, cg = lane >> 4;
            float X[4] = {0.f,0.f,0.f,0.f};
            for (int Kb = J; Kb < I; ++Kb) {
                #pragma unroll
                for (int p = 0; p < 16; ++p) {
                    float av = Am[I*16 + r][Kb*16 + p];
                    #pragma unroll
                    for (int mm = 0; mm < 4; ++mm)
                        X[mm] += av * Tm[Kb*16 + p][J*16 + cg + 4*mm];
                }
            }
            #pragma unroll
            for (int mm = 0; mm < 4; ++mm) Xs[wv][r][cg + 4*mm] = X[mm];
            float Y[4] = {0.f,0.f,0.f,0.f};
            #pragma unroll
            for (int p = 0; p < 16; ++p) {
                float td = Tm[I*16 + r][I*16 + p];
                #pragma unroll
                for (int mm = 0; mm < 4; ++mm)
                    Y[mm] += td * Xs[wv][p][cg + 4*mm];
            }
            #pragma unroll
            for (int mm = 0; mm < 4; ++mm)
                Tm[I*16 + r][J*16 + cg + 4*mm] = -Y[mm];
        }
    }
    __syncthreads();

    // MTt[s][t] = (Mm * Tm)[t][s]
    {
        float acc[16];
        #pragma unroll
        for (int j = 0; j < 16; ++j) acc[j] = 0.f;
        const int t = lane, sbase = wv * 16;
        for (int i4 = 0; i4 < 64; i4 += 4) {
            fl4 mv = *(const fl4*)&Mm[t][i4];
            #pragma unroll
            for (int sj = 0; sj < 16; ++sj) {
                int s = sbase + sj;
                acc[sj] += mv[0]*Tm[i4+0][s] + mv[1]*Tm[i4+1][s]
                         + mv[2]*Tm[i4+2][s] + mv[3]*Tm[i4+3][s];
            }
        }
        float* dst = MTt_g + (size_t)(c*NVH + h)*64*64;
        #pragma unroll
        for (int sj = 0; sj < 16; ++sj)
            dst[(sbase + sj)*64 + t] = acc[sj];
    }
    // SUt[s][d] = sum_t Dend[t]*K[t][d]*Tm[t][s]
    {
        float acc[16];
        #pragma unroll
        for (int j = 0; j < 16; ++j) acc[j] = 0.f;
        const int d = lane, sbase = wv * 16;
        for (int t = 0; t < 64; ++t) {
            float kd = Ks[t][d] * Dend[t];
            #pragma unroll
            for (int sj = 0; sj < 16; ++sj)
                acc[sj] += kd * Tm[t][sbase + sj];
        }
        float* dst = SUt_g + (size_t)(c*NVH + h)*64*64;
        #pragma unroll
        for (int sj = 0; sj < 16; ++sj)
            dst[(sbase + sj)*64 + d] = acc[sj];
    }
    // packed transposes (once per k-head)
    if ((h & 1) == 0) {
        float* kdst = KT_g + (size_t)(c*NKH + kh)*64*64;
        float* qdst = QT_g + (size_t)(c*NKH + kh)*64*64;
        const int t = lane;
        #pragma unroll
        for (int ii = 0; ii < 16; ++ii) {
            int i = wv*16 + ii;
            kdst[i*64 + t] = Ks[t][i];
            qdst[i*64 + t] = Qs[t][i];
        }
    }
}

// ---------------------------------------------------------------------------
// Kernel 3 (phase 2): sequential over 32 chunks; block = (head, 8-col slice).
// Per chunk: P=K*s0, O1=Q*s0  ->  w = beta*v - beta*gamma*P  ->
//            o = gamma*O1 + MT*w ; s0 = gamma_end*s0 + SU*w.
// ---------------------------------------------------------------------------
__global__ __launch_bounds__(256) void phase2_kernel(
    const float* __restrict__ vo, const float* __restrict__ bws,
    const float* __restrict__ gam_g, const float* __restrict__ KT_g,
    const float* __restrict__ QT_g, const float* __restrict__ MTt_g,
    const float* __restrict__ SUt_g, const float* __restrict__ rs0,
    float* __restrict__ out)
{
    const int bid = blockIdx.x;
    const int h = bid >> 3, jg = bid & 7, kh = h >> 1;
    const int tid = threadIdx.x, lane = tid & 63, wv = tid >> 6;

    __shared__ float s0[64][10], wbuf[64][10], O1s[64][10], red[4][64][10];

    {
        const int d = tid >> 2, j2 = (tid & 3) * 2;
        s0[d][j2]   = rs0[((size_t)h*64 + d)*64 + jg*8 + j2];
        s0[d][j2+1] = rs0[((size_t)h*64 + d)*64 + jg*8 + j2 + 1];
    }
    __syncthreads();

    const int t0 = (lane & 15) * 4;   // 4-row tile
    const int jp = (lane >> 4) * 2;   // 2-col tile

    for (int c = 0; c < NCHUNK; ++c) {
        const float* KTc  = KT_g  + (size_t)(c*NKH + kh)*64*64;
        const float* QTc  = QT_g  + (size_t)(c*NKH + kh)*64*64;
        const float* MTtc = MTt_g + (size_t)(c*NVH + h)*64*64;
        const float* SUtc = SUt_g + (size_t)(c*NVH + h)*64*64;
        const float* gamc = gam_g + (size_t)(c*NVH + h)*64;

        // Phase A: waves 0,1 -> P partials (inner halves); waves 2,3 -> O1
        {
            const float* Mx = (wv < 2) ? KTc : QTc;
            const int ib = (wv & 1) * 32;
            float p0[4], p1[4];
            #pragma unroll
            for (int r = 0; r < 4; ++r) { p0[r] = 0.f; p1[r] = 0.f; }
            for (int i = ib; i < ib + 32; ++i) {
                fl4 m = *(const fl4*)&Mx[i*64 + t0];
                float sa = s0[i][jp], sb = s0[i][jp+1];
                #pragma unroll
                for (int r = 0; r < 4; ++r) { p0[r] += m[r]*sa; p1[r] += m[r]*sb; }
            }
            #pragma unroll
            for (int r = 0; r < 4; ++r) {
                red[wv][t0 + r][jp]   = p0[r];
                red[wv][t0 + r][jp+1] = p1[r];
            }
        }
        __syncthreads();
        // finalize w, gamma*O1
        {
            const int t = tid >> 2, j2 = (tid & 3) * 2;
            const float bt = bws[(size_t)(c*64 + t)*NVH + h];
            const float gt = gamc[t];
            #pragma unroll
            for (int u = 0; u < 2; ++u) {
                int jj = j2 + u;
                float P  = red[0][t][jj] + red[1][t][jj];
                float O1 = red[2][t][jj] + red[3][t][jj];
                float vv = vo[(size_t)(c*64 + t)*VAL_DIM + h*64 + jg*8 + jj];
                wbuf[t][jj] = bt * vv - bt * gt * P;
                O1s[t][jj]  = gt * O1;
            }
        }
        __syncthreads();
        // Phase B: waves 0,1 -> MT*w; waves 2,3 -> SU*w
        {
            const float* Mx = (wv < 2) ? MTtc : SUtc;
            const int sb = (wv & 1) * 32;
            float p0[4], p1[4];
            #pragma unroll
            for (int r = 0; r < 4; ++r) { p0[r] = 0.f; p1[r] = 0.f; }
            for (int s = sb; s < sb + 32; ++s) {
                fl4 m = *(const fl4*)&Mx[s*64 + t0];
                float wa = wbuf[s][jp], wb = wbuf[s][jp+1];
                #pragma unroll
                for (int r = 0; r < 4; ++r) { p0[r] += m[r]*wa; p1[r] += m[r]*wb; }
            }
            #pragma unroll
            for (int r = 0; r < 4; ++r) {
                red[wv][t0 + r][jp]   = p0[r];
                red[wv][t0 + r][jp+1] = p1[r];
            }
        }
        __syncthreads();
        // finalize: out write + state update
        {
            const int t = tid >> 2, j2 = (tid & 3) * 2;
            const float gend = gamc[63];
            #pragma unroll
            for (int u = 0; u < 2; ++u) {
                int jj = j2 + u;
                float ov = O1s[t][jj] + red[0][t][jj] + red[1][t][jj];
                out[(size_t)(c*64 + t)*VAL_DIM + h*64 + jg*8 + jj] = ov;
                s0[t][jj] = gend * s0[t][jj] + red[2][t][jj] + red[3][t][jj];
            }
        }
        __syncthreads();
    }
}

// ---------------------------------------------------------------------------
// Fallback: original scan kernel (used only if ws_size is too small).
// ---------------------------------------------------------------------------
#define LOADSTEP(KA, QA, VV, GG, BB, tt) {                                     \
    _Pragma("unroll")                                                          \
    for (int i = 0; i < 4; ++i) {                                              \
        KA[i] = *(const fl4*)(kp + (size_t)(tt) * KEY_DIM + i * 4);            \
        QA[i] = *(const fl4*)(qp + (size_t)(tt) * KEY_DIM + i * 4);            \
    }                                                                          \
    VV = vp[(size_t)(tt) * VAL_DIM];                                           \
    GG = gp[(size_t)(tt) * NVH];                                               \
    BB = bp[(size_t)(tt) * NVH];                                               \
}

#define COMPUTE(KA, QA, VV, GG, BB, tt) {                                      \
    const float dec = __expf(GG);                                              \
    float c0 = 0.f, c1 = 0.f, c2 = 0.f, c3 = 0.f;                              \
    _Pragma("unroll")                                                          \
    for (int i = 0; i < 4; ++i) {                                              \
        S[i*4+0] *= dec; S[i*4+1] *= dec; S[i*4+2] *= dec; S[i*4+3] *= dec;    \
        c0 = fmaf(S[i*4+0], KA[i][0], c0);                                     \
        c1 = fmaf(S[i*4+1], KA[i][1], c1);                                     \
        c2 = fmaf(S[i*4+2], KA[i][2], c2);                                     \
        c3 = fmaf(S[i*4+3], KA[i][3], c3);                                     \
    }                                                                          \
    float kv = (c0 + c1) + (c2 + c3);                                          \
    kv += __shfl_xor(kv, 1);                                                   \
    kv += __shfl_xor(kv, 2);                                                   \
    const float u = BB * (VV - kv);                                            \
    float o0 = 0.f, o1 = 0.f, o2 = 0.f, o3 = 0.f;                              \
    _Pragma("unroll")                                                          \
    for (int i = 0; i < 4; ++i) {                                              \
        S[i*4+0] = fmaf(KA[i][0], u, S[i*4+0]);                                \
        S[i*4+1] = fmaf(KA[i][1], u, S[i*4+1]);                                \
        S[i*4+2] = fmaf(KA[i][2], u, S[i*4+2]);                                \
        S[i*4+3] = fmaf(KA[i][3], u, S[i*4+3]);                                \
        o0 = fmaf(S[i*4+0], QA[i][0], o0);                                     \
        o1 = fmaf(S[i*4+1], QA[i][1], o1);                                     \
        o2 = fmaf(S[i*4+2], QA[i][2], o2);                                     \
        o3 = fmaf(S[i*4+3], QA[i][3], o3);                                     \
    }                                                                          \
    float oo = (o0 + o1) + (o2 + o3);                                          \
    oo += __shfl_xor(oo, 1);                                                   \
    oo += __shfl_xor(oo, 2);                                                   \
    if (kg == 0) op[(size_t)(tt) * VAL_DIM] = oo;                              \
}

__global__ __launch_bounds__(256) void scan_kernel(
    const float* __restrict__ qn, const float* __restrict__ kn,
    const float* __restrict__ v, const float* __restrict__ g,
    const float* __restrict__ bet, const float* __restrict__ rs0,
    float* __restrict__ out)
{
    const int h    = blockIdx.x;
    const int kh   = h >> 1;
    const int tid  = threadIdx.x;
    const int vcol = tid >> 2;
    const int kg   = tid & 3;

    float S[16];
    #pragma unroll
    for (int j = 0; j < 16; ++j)
        S[j] = rs0[((size_t)h * HD + (kg * 16 + j)) * HD + vcol];

    const float* kp = kn + (size_t)kh * HD + kg * 16;
    const float* qp = qn + (size_t)kh * HD + kg * 16;
    const float* vp = v + (size_t)h * HD + vcol;
    const float* gp = g + h;
    const float* bp = bet + h;
    float*       op = out + (size_t)h * HD + vcol;

    fl4 ka0[4], qa0[4]; float vv0, gg0, bb0;
    fl4 ka1[4], qa1[4]; float vv1, gg1, bb1;

    LOADSTEP(ka0, qa0, vv0, gg0, bb0, 0);
    for (int t = 0; t < T_LEN; t += 2) {
        LOADSTEP(ka1, qa1, vv1, gg1, bb1, t + 1);
        COMPUTE(ka0, qa0, vv0, gg0, bb0, t);
        const int t2 = (t + 2 < T_LEN) ? (t + 2) : (T_LEN - 1);
        LOADSTEP(ka0, qa0, vv0, gg0, bb0, t2);
        COMPUTE(ka1, qa1, vv1, gg1, bb1, t + 1);
    }
}

// ---------------------------------------------------------------------------
extern "C" void kernel_launch(void* const* d_in, const int* in_sizes, int n_in,
                              void* d_out, int out_size, void* d_ws, size_t ws_size,
                              hipStream_t stream)
{
    const float* x       = (const float*)d_in[0];
    const float* cs      = (const float*)d_in[1];
    const float* rs0     = (const float*)d_in[2];
    const float* b       = (const float*)d_in[3];
    const float* a       = (const float*)d_in[4];
    const float* w       = (const float*)d_in[5];
    const float* A_log   = (const float*)d_in[6];
    const float* dt_bias = (const float*)d_in[7];
    float* out = (float*)d_out;

    float* ws = (float*)d_ws;
    size_t off = 0;
    float* qn  = ws + off; off += (size_t)T_LEN * KEY_DIM;
    float* kn  = ws + off; off += (size_t)T_LEN * KEY_DIM;
    float* vo  = ws + off; off += (size_t)T_LEN * VAL_DIM;
    float* g   = ws + off; off += (size_t)T_LEN * NVH;
    float* be  = ws + off; off += (size_t)T_LEN * NVH;
    float* gam = ws + off; off += (size_t)NCHUNK * NVH * 64;
    float* KT  = ws + off; off += (size_t)NCHUNK * NKH * 64 * 64;
    float* QT  = ws + off; off += (size_t)NCHUNK * NKH * 64 * 64;
    float* MTt = ws + off; off += (size_t)NCHUNK * NVH * 64 * 64;
    float* SUt = ws + off; off += (size_t)NCHUNK * NVH * 64 * 64;
    const size_t need = off * sizeof(float);

    prep_kernel<<<T_LEN, 256, 0, stream>>>(x, cs, w, b, a, A_log, dt_bias,
                                           qn, kn, vo, g, be);
    if (ws_size >= need) {
        phase1_kernel<<<NCHUNK * NVH, 256, 0, stream>>>(qn, kn, g, be,
                                                        gam, KT, QT, MTt, SUt);
        phase2_kernel<<<NVH * 8, 256, 0, stream>>>(vo, be, gam, KT, QT, MTt, SUt,
                                                   rs0, out);
    } else {
        scan_kernel<<<NVH, 256, 0, stream>>>(qn, kn, vo, g, be, rs0, out);
    }
}